// Round 1
// baseline (25980.780 us; speedup 1.0000x reference)
//
#include <hip/hip_runtime.h>
#include <math.h>

#define T_ 512

__device__ __forceinline__ double sigmd(double v) { return 1.0 / (1.0 + exp(-v)); }

// Coherent (agent-scope, cache-bypassing) 8-byte load/store — no fences needed.
__device__ __forceinline__ double hload(const double* p) {
  unsigned long long u = __hip_atomic_load((const unsigned long long*)p,
                                           __ATOMIC_RELAXED, __HIP_MEMORY_SCOPE_AGENT);
  return __builtin_bit_cast(double, u);
}
__device__ __forceinline__ void hstore(double* p, double v) {
  __hip_atomic_store((unsigned long long*)p, __builtin_bit_cast(unsigned long long, v),
                     __ATOMIC_RELAXED, __HIP_MEMORY_SCOPE_AGENT);
}

// A row kc lives at Alds + kc*9 + 2*(kc>>6). The +2 per 64-row block staggers
// the 8 in-wave k-team base addresses across banks; without it 64*9 doubles is
// bank-aligned (1152*2 % 32 == 0) -> 8-way conflict on every GEMM a-read.
__device__ __forceinline__ int aoff(int kc) { return kc * 9 + ((kc >> 6) << 1); }

// Grid 256 = 32 groups x 8 blocks; blockIdx = g*8 + w so XCD (blockIdx%8) == w
// caches only col-slice w's 512 KB of weights in its L2. Group g owns batch rows
// [8g, 8g+8); block w owns h-cols [32w, 32w+32) of BOTH layers.
// GEMM: wave = (layer, gate); lane = (kt 8, og 8): k-teams live INSIDE the wave
// so the 8 K=64 partials reduce with 3 shfl_xor rounds (no LDS RMW, no barriers).
__global__ __launch_bounds__(512, 2) void lstm2_head(
    const float* __restrict__ x, const float* __restrict__ W1,
    const float* __restrict__ b1, const float* __restrict__ W2,
    const float* __restrict__ b2, const float* __restrict__ Wo,
    const float* __restrict__ bo, float* __restrict__ out,
    unsigned char* __restrict__ ws)
{
  __shared__ double Alds[6936];   // [kc 768][r 8] stride 9, +2/64-row stagger (55.5 KB)
  __shared__ double zbuf[2112];   // [(half,gate) 8][r 8][32 +1 pad]  (16.9 KB)

  const int tid = threadIdx.x;
  const int g  = blockIdx.x >> 3;    // 0..31
  const int w  = blockIdx.x & 7;     // 0..7
  const int rb0 = g << 3;

  unsigned* bar = (unsigned*)ws + (g << 4);            // 64B-spaced counters
  double* hbase = (double*)(ws + 4096);
  double* h1g = hbase + (size_t)g * 4096;              // [2 slots][8 r][256]
  double* h2g = hbase + 131072 + (size_t)g * 4096;

  // Zero both slots of both h arrays (redundant across the group's blocks, benign).
  for (int i = tid; i < 4096; i += 512) { hstore(h1g + i, 0.0); hstore(h2g + i, 0.0); }

  // group barrier #0
  __builtin_amdgcn_s_waitcnt(0);
  __syncthreads();
  if (tid == 0) {
    __hip_atomic_fetch_add(bar, 1u, __ATOMIC_RELAXED, __HIP_MEMORY_SCOPE_AGENT);
    while (__hip_atomic_load(bar, __ATOMIC_RELAXED, __HIP_MEMORY_SCOPE_AGENT) < 8u)
      __builtin_amdgcn_s_sleep(1);
    __asm__ volatile("" ::: "memory");
  }
  __syncthreads();

  // ---- GEMM mapping ----
  const int lane = tid & 63;
  const int wvid = tid >> 6;               // wave 0..7
  const int half = wvid >> 2;              // 0 = layer1, 1 = layer2
  const int gate = wvid & 3;               // i,j,f,o
  const int kt   = lane >> 3;              // in-wave k-team 0..7 (K=64 each)
  const int og   = lane & 7;               // col-quad within the 32-col slice
  const float* wbase = (half ? W2 : W1)
      + (size_t)(kt << 6) * 1024 + (gate << 8) + (w << 5) + (og << 2);
  const int kc0  = (half << 8) + (kt << 6);
  const int zrow = ((half << 2) + gate) << 3;

  // ---- staging mapping ----
  const int sr  = tid & 7;                 // A-row
  const int skc = tid >> 3;                // 0..63

  // ---- update mapping: one cell per thread ----
  const int L  = tid >> 8;
  const int ur = (tid >> 5) & 7;
  const int hj = tid & 31;
  const float* ubb = L ? b2 : b1;
  const int ucol = (w << 5) + hj;
  const double ub_i = (double)ubb[ucol];
  const double ub_j = (double)ubb[256 + ucol];
  const double ub_f = (double)ubb[512 + ucol];
  const double ub_o = (double)ubb[768 + ucol];
  double cst = 0.0;

  // ---- head (block w==0): wave v owns row v; lane owns h2-cols {lane,64+,128+,192+}
  const bool headblk = (w == 0);
  float  wo_r[4][6];
  double bo_r[6];
  if (headblk) {
    #pragma unroll
    for (int q = 0; q < 4; ++q)
      #pragma unroll
      for (int c = 0; c < 6; ++c) wo_r[q][c] = Wo[(lane + (q << 6)) * 6 + c];
    #pragma unroll
    for (int c = 0; c < 6; ++c) bo_r[c] = (double)bo[c];
  }

  auto do_head = [&](int t3) {
    double pr[6] = {0, 0, 0, 0, 0, 0};
    #pragma unroll
    for (int q = 0; q < 4; ++q) {
      double hv = Alds[aoff(512 + lane + (q << 6)) + wvid];
      #pragma unroll
      for (int c = 0; c < 6; ++c) pr[c] = fma(hv, (double)wo_r[q][c], pr[c]);
    }
    #pragma unroll
    for (int off = 1; off <= 32; off <<= 1)
      #pragma unroll
      for (int c = 0; c < 6; ++c) pr[c] += __shfl_xor(pr[c], off, 64);
    if (lane == 0) {
      size_t orow = (((size_t)(rb0 + wvid)) << 9) + (size_t)t3;   // b*T + t
      #pragma unroll
      for (int c = 0; c < 6; ++c) {
        double lg = pr[c] + bo_r[c];
        out[orow * 6 + c] = (float)lg;
        float pd = (lg > 0.0) ? 1.0f : 0.0f;       // 0.5 < sigmoid <=> lg > 0
        out[(size_t)786432 + orow * 6 + c] = pd;   // condition
        out[(size_t)1572864 + orow * 6 + c] = pd;  // prediction
      }
    }
  };

  // ---- prologue stage for phase 0: x(0), h1(-1)=0, h2(-2)=0 ----
  {
    const float* xb = x + (size_t)(rb0 + sr) * (T_ * 256) + skc;   // t=0
    float xv[4];
    #pragma unroll
    for (int v = 0; v < 4; ++v) xv[v] = xb[v << 6];
    const double* h1p = h1g + 2048;   // slot 1 (zeroed)
    const double* h2p = h2g;          // slot 0 (zeroed)
    double hv8[8];
    #pragma unroll
    for (int v = 0; v < 4; ++v) hv8[v] = hload(h1p + (sr << 8) + skc + (v << 6));
    #pragma unroll
    for (int v = 0; v < 4; ++v) hv8[4 + v] = hload(h2p + (sr << 8) + skc + (v << 6));
    #pragma unroll
    for (int v = 0; v < 4; ++v) Alds[aoff((v << 6) + skc) + sr] = (double)xv[v];
    #pragma unroll
    for (int v = 0; v < 8; ++v) Alds[aoff(256 + (v << 6) + skc) + sr] = hv8[v];
  }
  __syncthreads();

  // Phase p: layer1(t=p), layer2(t=p-1), head(t=p-2).
  #pragma unroll 1
  for (int p = 0; p <= T_ + 1; ++p) {
    // ---- GEMM: lane covers 4 gate-cols x 8 rows over k in [64kt, 64kt+64).
    // Ping-pong 8-deep float4 weight prefetch keeps >=8 loads in flight.
    double acc[4][8];
    #pragma unroll
    for (int c = 0; c < 4; ++c)
      #pragma unroll
      for (int r = 0; r < 8; ++r) acc[c][r] = 0.0;
    {
      const float* wp = wbase;
      const double* ap = Alds + aoff(kc0);
      float4 wva[8], wvb[8];
      #pragma unroll
      for (int j = 0; j < 8; ++j) wva[j] = *(const float4*)(wp + (size_t)j * 1024);
      #pragma unroll 1
      for (int sg = 0; sg < 4; ++sg) {
        const int s0 = sg << 4;
        #pragma unroll
        for (int j = 0; j < 8; ++j)
          wvb[j] = *(const float4*)(wp + (size_t)(s0 + 8 + j) * 1024);
        #pragma unroll
        for (int j = 0; j < 8; ++j) {
          const double* apj = ap + (s0 + j) * 9;
          double a[8];
          #pragma unroll
          for (int r = 0; r < 8; ++r) a[r] = apj[r];
          const double w0 = (double)wva[j].x, w1 = (double)wva[j].y;
          const double w2 = (double)wva[j].z, w3 = (double)wva[j].w;
          #pragma unroll
          for (int r = 0; r < 8; ++r) {
            acc[0][r] = fma(a[r], w0, acc[0][r]);
            acc[1][r] = fma(a[r], w1, acc[1][r]);
            acc[2][r] = fma(a[r], w2, acc[2][r]);
            acc[3][r] = fma(a[r], w3, acc[3][r]);
          }
        }
        if (sg < 3) {
          #pragma unroll
          for (int j = 0; j < 8; ++j)
            wva[j] = *(const float4*)(wp + (size_t)(s0 + 16 + j) * 1024);
        }
        #pragma unroll
        for (int j = 0; j < 8; ++j) {
          const double* apj = ap + (s0 + 8 + j) * 9;
          double a[8];
          #pragma unroll
          for (int r = 0; r < 8; ++r) a[r] = apj[r];
          const double w0 = (double)wvb[j].x, w1 = (double)wvb[j].y;
          const double w2 = (double)wvb[j].z, w3 = (double)wvb[j].w;
          #pragma unroll
          for (int r = 0; r < 8; ++r) {
            acc[0][r] = fma(a[r], w0, acc[0][r]);
            acc[1][r] = fma(a[r], w1, acc[1][r]);
            acc[2][r] = fma(a[r], w2, acc[2][r]);
            acc[3][r] = fma(a[r], w3, acc[3][r]);
          }
        }
      }
    }

    // ---- in-wave k-team reduce: xor over lane bits 3..5 (kt), og preserved ----
    #pragma unroll
    for (int c = 0; c < 4; ++c)
      #pragma unroll
      for (int r = 0; r < 8; ++r) {
        double v = acc[c][r];
        v += __shfl_xor(v, 8, 64);
        v += __shfl_xor(v, 16, 64);
        v += __shfl_xor(v, 32, 64);
        acc[c][r] = v;
      }

    // ---- z write: kt-group kt writes row r=kt (static acc indexing, predicated) ----
    #pragma unroll
    for (int r = 0; r < 8; ++r) {
      if (kt == r) {
        #pragma unroll
        for (int c = 0; c < 4; ++c)
          zbuf[(zrow + r) * 33 + (og << 2) + c] = acc[c][r];
      }
    }
    __syncthreads();   // #1: z ready

    // ---- Cell update: gates (i,j,f,o), forget bias 1.0 ----
    {
      const bool uact = L ? (p >= 1 && p <= T_) : (p < T_);
      if (uact) {
        const double* za = zbuf + ((L << 5) + ur) * 33 + hj;
        double zi = za[0]   + ub_i;
        double zj = za[264] + ub_j;
        double zf = za[528] + ub_f;
        double zo = za[792] + ub_o;
        cst = cst * sigmd(zf + 1.0) + sigmd(zi) * tanh(zj);
        double hv = tanh(cst) * sigmd(zo);
        double* hd = L ? (h2g + (((p + 1) & 1) << 11)) : (h1g + ((p & 1) << 11));
        hstore(hd + (ur << 8) + ucol, hv);
      }
    }

    if (p <= T_) {
      // ---- arrive early, then hide head + x-prefetch in the barrier shadow ----
      __builtin_amdgcn_s_waitcnt(0);
      __syncthreads();   // #2: all waves' h stores drained
      if (tid == 0)
        __hip_atomic_fetch_add(bar, 1u, __ATOMIC_RELAXED, __HIP_MEMORY_SCOPE_AGENT);

      // x prefetch for phase p+1 (no cross-block dependency)
      const int xp1 = (p + 1 < T_) ? (p + 1) : (T_ - 1);
      const float* xb = x + (size_t)(rb0 + sr) * (T_ * 256) + (size_t)xp1 * 256 + skc;
      float xv[4];
      #pragma unroll
      for (int v = 0; v < 4; ++v) xv[v] = xb[v << 6];

      // head t3=p-2 from staged h2 region (Alds [512,768) untouched until after #3)
      if (headblk && p >= 2) do_head(p - 2);

      // x LDS writes: region [0,256) — disjoint from head reads, GEMM long done
      #pragma unroll
      for (int v = 0; v < 4; ++v) Alds[aoff((v << 6) + skc) + sr] = (double)xv[v];

      if (tid == 0) {
        const unsigned target = ((unsigned)(p + 2)) << 3;
        while (__hip_atomic_load(bar, __ATOMIC_RELAXED, __HIP_MEMORY_SCOPE_AGENT) < target)
          __builtin_amdgcn_s_sleep(1);
        __asm__ volatile("" ::: "memory");
      }
      __syncthreads();   // #3: group h published

      // ---- stage h1(p), h2(p-1) for phase p+1 ----
      const double* h1p = h1g + ((p & 1) << 11);
      const double* h2p = h2g + (((p + 1) & 1) << 11);
      double hv8[8];
      #pragma unroll
      for (int v = 0; v < 4; ++v) hv8[v] = hload(h1p + (sr << 8) + skc + (v << 6));
      #pragma unroll
      for (int v = 0; v < 4; ++v) hv8[4 + v] = hload(h2p + (sr << 8) + skc + (v << 6));
      #pragma unroll
      for (int v = 0; v < 8; ++v) Alds[aoff(256 + (v << 6) + skc) + sr] = hv8[v];
      __syncthreads();   // #4: A staged for next phase
    } else {
      // final phase: emit last head (t3 = T_-1), no barrier/stage needed
      if (headblk) do_head(p - 2);
    }
  }
}

extern "C" void kernel_launch(void* const* d_in, const int* in_sizes, int n_in,
                              void* d_out, int out_size, void* d_ws, size_t ws_size,
                              hipStream_t stream) {
  const float* x  = (const float*)d_in[0];
  const float* W1 = (const float*)d_in[1];
  const float* b1 = (const float*)d_in[2];
  const float* W2 = (const float*)d_in[3];
  const float* b2 = (const float*)d_in[4];
  const float* Wo = (const float*)d_in[5];
  const float* bo = (const float*)d_in[6];
  float* out = (float*)d_out;
  unsigned char* ws = (unsigned char*)d_ws;

  // Zero barrier counters (first 4 KB of ws); part of the captured graph.
  hipMemsetAsync(d_ws, 0, 4096, stream);

  lstm2_head<<<dim3(256), dim3(512), 0, stream>>>(x, W1, b1, W2, b2, Wo, bo, out, ws);
}

// Round 2
// 12331.057 us; speedup vs baseline: 2.1069x; 2.1069x over previous
//
#include <hip/hip_runtime.h>
#include <math.h>

#define T_ 512

__device__ __forceinline__ double sigmd(double v) { return 1.0 / (1.0 + exp(-v)); }

// Coherent (agent-scope, cache-bypassing) 8-byte load/store — no fences needed.
__device__ __forceinline__ double hload(const double* p) {
  unsigned long long u = __hip_atomic_load((const unsigned long long*)p,
                                           __ATOMIC_RELAXED, __HIP_MEMORY_SCOPE_AGENT);
  return __builtin_bit_cast(double, u);
}
__device__ __forceinline__ void hstore(double* p, double v) {
  __hip_atomic_store((unsigned long long*)p, __builtin_bit_cast(unsigned long long, v),
                     __ATOMIC_RELAXED, __HIP_MEMORY_SCOPE_AGENT);
}

// A row kc lives at Alds + kc*9 + 2*(kc>>6). The +2 per 64-row block staggers
// the 8 in-wave k-team base addresses across banks; without it 64*9 doubles is
// bank-aligned (1152*2 % 32 == 0) -> 8-way conflict on every GEMM a-read.
__device__ __forceinline__ int aoff(int kc) { return kc * 9 + ((kc >> 6) << 1); }

// Grid 256 = 32 groups x 8 blocks; blockIdx = g*8 + w so XCD (blockIdx%8) == w
// caches only col-slice w's 512 KB of weights in its L2. Group g owns batch rows
// [8g, 8g+8); block w owns h-cols [32w, 32w+32) of BOTH layers.
// GEMM: wave = (layer, gate); lane = (kt 8, og 8): k-teams live INSIDE the wave
// so the 8 K=64 partials reduce with 3 shfl_xor rounds (no LDS RMW, no barriers).
// launch_bounds (512,1): grid==256 blocks on 256 CUs -> only 1 block/CU ever;
// (512,2) capped the allocator at 128 VGPRs and caused catastrophic spill (R1).
__global__ __launch_bounds__(512, 1) void lstm2_head(
    const float* __restrict__ x, const float* __restrict__ W1,
    const float* __restrict__ b1, const float* __restrict__ W2,
    const float* __restrict__ b2, const float* __restrict__ Wo,
    const float* __restrict__ bo, float* __restrict__ out,
    unsigned char* __restrict__ ws)
{
  __shared__ double Alds[6936];   // [kc 768][r 8] stride 9, +2/64-row stagger (55.5 KB)
  __shared__ double zbuf[2112];   // [(half,gate) 8][r 8][32 +1 pad]  (16.9 KB)

  const int tid = threadIdx.x;
  const int g  = blockIdx.x >> 3;    // 0..31
  const int w  = blockIdx.x & 7;     // 0..7
  const int rb0 = g << 3;

  unsigned* bar = (unsigned*)ws + (g << 4);            // 64B-spaced counters
  double* hbase = (double*)(ws + 4096);
  double* h1g = hbase + (size_t)g * 4096;              // [2 slots][8 r][256]
  double* h2g = hbase + 131072 + (size_t)g * 4096;

  // Zero both slots of both h arrays (redundant across the group's blocks, benign).
  for (int i = tid; i < 4096; i += 512) { hstore(h1g + i, 0.0); hstore(h2g + i, 0.0); }

  // group barrier #0
  __builtin_amdgcn_s_waitcnt(0);
  __syncthreads();
  if (tid == 0) {
    __hip_atomic_fetch_add(bar, 1u, __ATOMIC_RELAXED, __HIP_MEMORY_SCOPE_AGENT);
    while (__hip_atomic_load(bar, __ATOMIC_RELAXED, __HIP_MEMORY_SCOPE_AGENT) < 8u)
      __builtin_amdgcn_s_sleep(1);
    __asm__ volatile("" ::: "memory");
  }
  __syncthreads();

  // ---- GEMM mapping ----
  const int lane = tid & 63;
  const int wvid = tid >> 6;               // wave 0..7
  const int half = wvid >> 2;              // 0 = layer1, 1 = layer2
  const int gate = wvid & 3;               // i,j,f,o
  const int kt   = lane >> 3;              // in-wave k-team 0..7 (K=64 each)
  const int og   = lane & 7;               // col-quad within the 32-col slice
  const float* wbase = (half ? W2 : W1)
      + (size_t)(kt << 6) * 1024 + (gate << 8) + (w << 5) + (og << 2);
  const int kc0  = (half << 8) + (kt << 6);
  const int zrow = ((half << 2) + gate) << 3;

  // ---- staging mapping ----
  const int sr  = tid & 7;                 // A-row
  const int skc = tid >> 3;                // 0..63

  // ---- update mapping: one cell per thread ----
  const int L  = tid >> 8;
  const int ur = (tid >> 5) & 7;
  const int hj = tid & 31;
  const float* ubb = L ? b2 : b1;
  const int ucol = (w << 5) + hj;
  const double ub_i = (double)ubb[ucol];
  const double ub_j = (double)ubb[256 + ucol];
  const double ub_f = (double)ubb[512 + ucol];
  const double ub_o = (double)ubb[768 + ucol];
  double cst = 0.0;

  // ---- head (block w==0): wave v owns row v; lane owns h2-cols {lane,64+,128+,192+}
  const bool headblk = (w == 0);
  float  wo_r[4][6];
  double bo_r[6];
  if (headblk) {
    #pragma unroll
    for (int q = 0; q < 4; ++q)
      #pragma unroll
      for (int c = 0; c < 6; ++c) wo_r[q][c] = Wo[(lane + (q << 6)) * 6 + c];
    #pragma unroll
    for (int c = 0; c < 6; ++c) bo_r[c] = (double)bo[c];
  }

  auto do_head = [&](int t3) {
    double pr[6] = {0, 0, 0, 0, 0, 0};
    #pragma unroll
    for (int q = 0; q < 4; ++q) {
      double hv = Alds[aoff(512 + lane + (q << 6)) + wvid];
      #pragma unroll
      for (int c = 0; c < 6; ++c) pr[c] = fma(hv, (double)wo_r[q][c], pr[c]);
    }
    #pragma unroll
    for (int off = 1; off <= 32; off <<= 1)
      #pragma unroll
      for (int c = 0; c < 6; ++c) pr[c] += __shfl_xor(pr[c], off, 64);
    if (lane == 0) {
      size_t orow = (((size_t)(rb0 + wvid)) << 9) + (size_t)t3;   // b*T + t
      #pragma unroll
      for (int c = 0; c < 6; ++c) {
        double lg = pr[c] + bo_r[c];
        out[orow * 6 + c] = (float)lg;
        float pd = (lg > 0.0) ? 1.0f : 0.0f;       // 0.5 < sigmoid <=> lg > 0
        out[(size_t)786432 + orow * 6 + c] = pd;   // condition
        out[(size_t)1572864 + orow * 6 + c] = pd;  // prediction
      }
    }
  };

  // ---- prologue stage for phase 0: x(0), h1(-1)=0, h2(-2)=0 ----
  {
    const float* xb = x + (size_t)(rb0 + sr) * (T_ * 256) + skc;   // t=0
    float xv[4];
    #pragma unroll
    for (int v = 0; v < 4; ++v) xv[v] = xb[v << 6];
    const double* h1p = h1g + 2048;   // slot 1 (zeroed)
    const double* h2p = h2g;          // slot 0 (zeroed)
    double hv8[8];
    #pragma unroll
    for (int v = 0; v < 4; ++v) hv8[v] = hload(h1p + (sr << 8) + skc + (v << 6));
    #pragma unroll
    for (int v = 0; v < 4; ++v) hv8[4 + v] = hload(h2p + (sr << 8) + skc + (v << 6));
    #pragma unroll
    for (int v = 0; v < 4; ++v) Alds[aoff((v << 6) + skc) + sr] = (double)xv[v];
    #pragma unroll
    for (int v = 0; v < 8; ++v) Alds[aoff(256 + (v << 6) + skc) + sr] = hv8[v];
  }
  __syncthreads();

  // Phase p: layer1(t=p), layer2(t=p-1), head(t=p-2).
  #pragma unroll 1
  for (int p = 0; p <= T_ + 1; ++p) {
    // ---- GEMM: lane covers 4 gate-cols x 8 rows over k in [64kt, 64kt+64).
    // Ping-pong 4+4 float4 weight prefetch (up to 8 in flight at switch points,
    // 32 VGPRs of buffer — fits the 256-reg budget without spill).
    double acc[4][8];
    #pragma unroll
    for (int c = 0; c < 4; ++c)
      #pragma unroll
      for (int r = 0; r < 8; ++r) acc[c][r] = 0.0;
    {
      const float* wp = wbase;
      const double* ap = Alds + aoff(kc0);
      float4 wva[4], wvb[4];
      #pragma unroll
      for (int j = 0; j < 4; ++j) wva[j] = *(const float4*)(wp + (size_t)j * 1024);
      #pragma unroll 1
      for (int sg = 0; sg < 8; ++sg) {
        const int s0 = sg << 3;
        #pragma unroll
        for (int j = 0; j < 4; ++j)
          wvb[j] = *(const float4*)(wp + (size_t)(s0 + 4 + j) * 1024);
        #pragma unroll
        for (int j = 0; j < 4; ++j) {
          const double* apj = ap + (s0 + j) * 9;
          double a[8];
          #pragma unroll
          for (int r = 0; r < 8; ++r) a[r] = apj[r];
          const double w0 = (double)wva[j].x, w1 = (double)wva[j].y;
          const double w2 = (double)wva[j].z, w3 = (double)wva[j].w;
          #pragma unroll
          for (int r = 0; r < 8; ++r) {
            acc[0][r] = fma(a[r], w0, acc[0][r]);
            acc[1][r] = fma(a[r], w1, acc[1][r]);
            acc[2][r] = fma(a[r], w2, acc[2][r]);
            acc[3][r] = fma(a[r], w3, acc[3][r]);
          }
        }
        if (sg < 7) {
          #pragma unroll
          for (int j = 0; j < 4; ++j)
            wva[j] = *(const float4*)(wp + (size_t)(s0 + 8 + j) * 1024);
        }
        #pragma unroll
        for (int j = 0; j < 4; ++j) {
          const double* apj = ap + (s0 + 4 + j) * 9;
          double a[8];
          #pragma unroll
          for (int r = 0; r < 8; ++r) a[r] = apj[r];
          const double w0 = (double)wvb[j].x, w1 = (double)wvb[j].y;
          const double w2 = (double)wvb[j].z, w3 = (double)wvb[j].w;
          #pragma unroll
          for (int r = 0; r < 8; ++r) {
            acc[0][r] = fma(a[r], w0, acc[0][r]);
            acc[1][r] = fma(a[r], w1, acc[1][r]);
            acc[2][r] = fma(a[r], w2, acc[2][r]);
            acc[3][r] = fma(a[r], w3, acc[3][r]);
          }
        }
      }
    }

    // ---- in-wave k-team reduce: xor over lane bits 3..5 (kt), og preserved ----
    #pragma unroll
    for (int c = 0; c < 4; ++c)
      #pragma unroll
      for (int r = 0; r < 8; ++r) {
        double v = acc[c][r];
        v += __shfl_xor(v, 8, 64);
        v += __shfl_xor(v, 16, 64);
        v += __shfl_xor(v, 32, 64);
        acc[c][r] = v;
      }

    // ---- z write: kt-group kt writes row r=kt (static acc indexing, predicated) ----
    #pragma unroll
    for (int r = 0; r < 8; ++r) {
      if (kt == r) {
        #pragma unroll
        for (int c = 0; c < 4; ++c)
          zbuf[(zrow + r) * 33 + (og << 2) + c] = acc[c][r];
      }
    }
    __syncthreads();   // #1: z ready

    // ---- Cell update: gates (i,j,f,o), forget bias 1.0 ----
    {
      const bool uact = L ? (p >= 1 && p <= T_) : (p < T_);
      if (uact) {
        const double* za = zbuf + ((L << 5) + ur) * 33 + hj;
        double zi = za[0]   + ub_i;
        double zj = za[264] + ub_j;
        double zf = za[528] + ub_f;
        double zo = za[792] + ub_o;
        cst = cst * sigmd(zf + 1.0) + sigmd(zi) * tanh(zj);
        double hv = tanh(cst) * sigmd(zo);
        double* hd = L ? (h2g + (((p + 1) & 1) << 11)) : (h1g + ((p & 1) << 11));
        hstore(hd + (ur << 8) + ucol, hv);
      }
    }

    if (p <= T_) {
      // ---- arrive early, then hide head + x-prefetch in the barrier shadow ----
      __builtin_amdgcn_s_waitcnt(0);
      __syncthreads();   // #2: all waves' h stores drained
      if (tid == 0)
        __hip_atomic_fetch_add(bar, 1u, __ATOMIC_RELAXED, __HIP_MEMORY_SCOPE_AGENT);

      // x prefetch for phase p+1 (no cross-block dependency)
      const int xp1 = (p + 1 < T_) ? (p + 1) : (T_ - 1);
      const float* xb = x + (size_t)(rb0 + sr) * (T_ * 256) + (size_t)xp1 * 256 + skc;
      float xv[4];
      #pragma unroll
      for (int v = 0; v < 4; ++v) xv[v] = xb[v << 6];

      // head t3=p-2 from staged h2 region (Alds [512,768) untouched until after #3)
      if (headblk && p >= 2) do_head(p - 2);

      // x LDS writes: region [0,256) — disjoint from head reads, GEMM long done
      #pragma unroll
      for (int v = 0; v < 4; ++v) Alds[aoff((v << 6) + skc) + sr] = (double)xv[v];

      if (tid == 0) {
        const unsigned target = ((unsigned)(p + 2)) << 3;
        while (__hip_atomic_load(bar, __ATOMIC_RELAXED, __HIP_MEMORY_SCOPE_AGENT) < target)
          __builtin_amdgcn_s_sleep(1);
        __asm__ volatile("" ::: "memory");
      }
      __syncthreads();   // #3: group h published

      // ---- stage h1(p), h2(p-1) for phase p+1 ----
      const double* h1p = h1g + ((p & 1) << 11);
      const double* h2p = h2g + (((p + 1) & 1) << 11);
      double hv8[8];
      #pragma unroll
      for (int v = 0; v < 4; ++v) hv8[v] = hload(h1p + (sr << 8) + skc + (v << 6));
      #pragma unroll
      for (int v = 0; v < 4; ++v) hv8[4 + v] = hload(h2p + (sr << 8) + skc + (v << 6));
      #pragma unroll
      for (int v = 0; v < 8; ++v) Alds[aoff(256 + (v << 6) + skc) + sr] = hv8[v];
      __syncthreads();   // #4: A staged for next phase
    } else {
      // final phase: emit last head (t3 = T_-1), no barrier/stage needed
      if (headblk) do_head(p - 2);
    }
  }
}

extern "C" void kernel_launch(void* const* d_in, const int* in_sizes, int n_in,
                              void* d_out, int out_size, void* d_ws, size_t ws_size,
                              hipStream_t stream) {
  const float* x  = (const float*)d_in[0];
  const float* W1 = (const float*)d_in[1];
  const float* b1 = (const float*)d_in[2];
  const float* W2 = (const float*)d_in[3];
  const float* b2 = (const float*)d_in[4];
  const float* Wo = (const float*)d_in[5];
  const float* bo = (const float*)d_in[6];
  float* out = (float*)d_out;
  unsigned char* ws = (unsigned char*)d_ws;

  // Zero barrier counters (first 4 KB of ws); part of the captured graph.
  hipMemsetAsync(d_ws, 0, 4096, stream);

  lstm2_head<<<dim3(256), dim3(512), 0, stream>>>(x, W1, b1, W2, b2, Wo, bo, out, ws);
}

// Round 3
// 7063.216 us; speedup vs baseline: 3.6783x; 1.7458x over previous
//
#include <hip/hip_runtime.h>
#include <math.h>

#define T_ 512

__device__ __forceinline__ double sigmd(double v) { return 1.0 / (1.0 + exp(-v)); }

// Coherent (agent-scope, cache-bypassing) 4-byte load/store for fp32 h exchange.
__device__ __forceinline__ float hloadf(const float* p) {
  unsigned u = __hip_atomic_load((const unsigned*)p,
                                 __ATOMIC_RELAXED, __HIP_MEMORY_SCOPE_AGENT);
  return __builtin_bit_cast(float, u);
}
__device__ __forceinline__ void hstoref(float* p, float v) {
  __hip_atomic_store((unsigned*)p, __builtin_bit_cast(unsigned, v),
                     __ATOMIC_RELAXED, __HIP_MEMORY_SCOPE_AGENT);
}

// fp32 A row kc at Alds + kc*8 + 4*(kc>>6): 32B rows, 16B-aligned (b128-able).
// The +4-float stagger per 64-row block puts the 8 in-wave k-team bases at
// banks {4kt}: each ds_read_b128 covers banks [4kt,4kt+4) -> 8 chunks tile all
// 32 banks, conflict-free, with og-lanes sharing addresses (free broadcast).
__device__ __forceinline__ int aoff_f(int kc) { return (kc << 3) + ((kc >> 6) << 2); }

// Grid 256 = 32 groups x 8 blocks; blockIdx = g*8 + w so XCD (blockIdx%8) == w
// caches only col-slice w's 512 KB of weights in its L2. Group g owns batch rows
// [8g, 8g+8); block w owns h-cols [32w, 32w+32) of BOTH layers.
// GEMM: wave = (layer, gate); lane = (kt 8, og 8); fp32 FMA, fp32 A/weights;
// k-team partials reduced with 3 b32 shfl_xor rounds. Cell update stays fp64
// (c-state fidelity); z and h are fp32 — same dtype as the JAX reference path.
__global__ __launch_bounds__(512, 1) void lstm2_head(
    const float* __restrict__ x, const float* __restrict__ W1,
    const float* __restrict__ b1, const float* __restrict__ W2,
    const float* __restrict__ b2, const float* __restrict__ Wo,
    const float* __restrict__ bo, float* __restrict__ out,
    unsigned char* __restrict__ ws)
{
  __shared__ float Alds[6192];   // [kc 768][r 8] stride 8 + stagger (24.8 KB)
  __shared__ float zbuf[2112];   // [(half,gate,r) 64][32 +1 pad] (8.4 KB)

  const int tid = threadIdx.x;
  const int g  = blockIdx.x >> 3;    // 0..31
  const int w  = blockIdx.x & 7;     // 0..7
  const int rb0 = g << 3;

  unsigned* bar = (unsigned*)ws + (g << 4);            // 64B-spaced counters
  float* hbase = (float*)(ws + 4096);
  float* h1g = hbase + (size_t)g * 4096;               // [2 slots][8 r][256] fp32
  float* h2g = hbase + 131072 + (size_t)g * 4096;

  // Zero both slots of both h arrays (redundant across the group's blocks, benign).
  for (int i = tid; i < 4096; i += 512) { hstoref(h1g + i, 0.0f); hstoref(h2g + i, 0.0f); }

  // group barrier #0
  __builtin_amdgcn_s_waitcnt(0);
  __syncthreads();
  if (tid == 0) {
    __hip_atomic_fetch_add(bar, 1u, __ATOMIC_RELAXED, __HIP_MEMORY_SCOPE_AGENT);
    while (__hip_atomic_load(bar, __ATOMIC_RELAXED, __HIP_MEMORY_SCOPE_AGENT) < 8u)
      __builtin_amdgcn_s_sleep(1);
    __asm__ volatile("" ::: "memory");
  }
  __syncthreads();

  // ---- GEMM mapping ----
  const int lane = tid & 63;
  const int wvid = tid >> 6;               // wave 0..7
  const int half = wvid >> 2;              // 0 = layer1, 1 = layer2
  const int gate = wvid & 3;               // i,j,f,o
  const int kt   = lane >> 3;              // in-wave k-team 0..7 (K=64 each)
  const int og   = lane & 7;               // col-quad within the 32-col slice
  const float* wbase = (half ? W2 : W1)
      + (size_t)(kt << 6) * 1024 + (gate << 8) + (w << 5) + (og << 2);
  const int kc0  = (half << 8) + (kt << 6);
  const int zrow = ((half << 2) + gate) << 3;

  // ---- staging mapping ----
  const int sr  = tid & 7;                 // A-row
  const int skc = tid >> 3;                // 0..63

  // ---- update mapping: one cell per thread (fp64 gates + c-state) ----
  const int L  = tid >> 8;
  const int ur = (tid >> 5) & 7;
  const int hj = tid & 31;
  const float* ubb = L ? b2 : b1;
  const int ucol = (w << 5) + hj;
  const double ub_i = (double)ubb[ucol];
  const double ub_j = (double)ubb[256 + ucol];
  const double ub_f = (double)ubb[512 + ucol];
  const double ub_o = (double)ubb[768 + ucol];
  double cst = 0.0;

  // ---- head (block w==0): wave v owns row v; lane owns h2-cols {lane,64+,128+,192+}
  const bool headblk = (w == 0);
  float  wo_r[4][6];
  double bo_r[6];
  if (headblk) {
    #pragma unroll
    for (int q = 0; q < 4; ++q)
      #pragma unroll
      for (int c = 0; c < 6; ++c) wo_r[q][c] = Wo[(lane + (q << 6)) * 6 + c];
    #pragma unroll
    for (int c = 0; c < 6; ++c) bo_r[c] = (double)bo[c];
  }

  auto do_head = [&](int t3) {
    double pr[6] = {0, 0, 0, 0, 0, 0};
    #pragma unroll
    for (int q = 0; q < 4; ++q) {
      double hv = (double)Alds[aoff_f(512 + lane + (q << 6)) + wvid];
      #pragma unroll
      for (int c = 0; c < 6; ++c) pr[c] = fma(hv, (double)wo_r[q][c], pr[c]);
    }
    #pragma unroll
    for (int off = 1; off <= 32; off <<= 1)
      #pragma unroll
      for (int c = 0; c < 6; ++c) pr[c] += __shfl_xor(pr[c], off, 64);
    if (lane == 0) {
      size_t orow = (((size_t)(rb0 + wvid)) << 9) + (size_t)t3;   // b*T + t
      #pragma unroll
      for (int c = 0; c < 6; ++c) {
        double lg = pr[c] + bo_r[c];
        out[orow * 6 + c] = (float)lg;
        float pd = (lg > 0.0) ? 1.0f : 0.0f;       // 0.5 < sigmoid <=> lg > 0
        out[(size_t)786432 + orow * 6 + c] = pd;   // condition
        out[(size_t)1572864 + orow * 6 + c] = pd;  // prediction
      }
    }
  };

  // ---- prologue stage for phase 0: x(0), h1(-1)=0, h2(-2)=0 ----
  {
    const float* xb = x + (size_t)(rb0 + sr) * (T_ * 256) + skc;   // t=0
    float sv[12];
    #pragma unroll
    for (int v = 0; v < 4; ++v) sv[v] = xb[v << 6];
    const float* h1p = h1g + 2048;   // slot 1 (zeroed)
    const float* h2p = h2g;          // slot 0 (zeroed)
    #pragma unroll
    for (int v = 0; v < 4; ++v) sv[4 + v] = hloadf(h1p + (sr << 8) + skc + (v << 6));
    #pragma unroll
    for (int v = 0; v < 4; ++v) sv[8 + v] = hloadf(h2p + (sr << 8) + skc + (v << 6));
    #pragma unroll
    for (int v = 0; v < 12; ++v) Alds[aoff_f((v << 6) + skc) + sr] = sv[v];
  }
  __syncthreads();

  // Phase p: layer1(t=p), layer2(t=p-1), head(t=p-2).
  #pragma unroll 1
  for (int p = 0; p <= T_ + 1; ++p) {
    // ---- GEMM: lane covers 4 gate-cols x 8 rows over k in [64kt, 64kt+64).
    // fp32 FMA; A via 2x ds_read_b128 per k (16B-aligned, conflict-free);
    // weights via 4+4 float4 ping-pong prefetch.
    float acc[4][8];
    #pragma unroll
    for (int c = 0; c < 4; ++c)
      #pragma unroll
      for (int r = 0; r < 8; ++r) acc[c][r] = 0.0f;
    {
      const float* wp = wbase;
      const float* ap = Alds + aoff_f(kc0);
      float4 wva[4], wvb[4];
      #pragma unroll
      for (int j = 0; j < 4; ++j) wva[j] = *(const float4*)(wp + (size_t)j * 1024);
      #pragma unroll 1
      for (int sg = 0; sg < 8; ++sg) {
        const int s0 = sg << 3;
        #pragma unroll
        for (int j = 0; j < 4; ++j)
          wvb[j] = *(const float4*)(wp + (size_t)(s0 + 4 + j) * 1024);
        #pragma unroll
        for (int j = 0; j < 4; ++j) {
          const float* apj = ap + ((s0 + j) << 3);
          float4 a0 = *(const float4*)(apj);
          float4 a1 = *(const float4*)(apj + 4);
          float a[8] = {a0.x, a0.y, a0.z, a0.w, a1.x, a1.y, a1.z, a1.w};
          #pragma unroll
          for (int r = 0; r < 8; ++r) {
            acc[0][r] = fmaf(a[r], wva[j].x, acc[0][r]);
            acc[1][r] = fmaf(a[r], wva[j].y, acc[1][r]);
            acc[2][r] = fmaf(a[r], wva[j].z, acc[2][r]);
            acc[3][r] = fmaf(a[r], wva[j].w, acc[3][r]);
          }
        }
        if (sg < 7) {
          #pragma unroll
          for (int j = 0; j < 4; ++j)
            wva[j] = *(const float4*)(wp + (size_t)(s0 + 8 + j) * 1024);
        }
        #pragma unroll
        for (int j = 0; j < 4; ++j) {
          const float* apj = ap + ((s0 + 4 + j) << 3);
          float4 a0 = *(const float4*)(apj);
          float4 a1 = *(const float4*)(apj + 4);
          float a[8] = {a0.x, a0.y, a0.z, a0.w, a1.x, a1.y, a1.z, a1.w};
          #pragma unroll
          for (int r = 0; r < 8; ++r) {
            acc[0][r] = fmaf(a[r], wvb[j].x, acc[0][r]);
            acc[1][r] = fmaf(a[r], wvb[j].y, acc[1][r]);
            acc[2][r] = fmaf(a[r], wvb[j].z, acc[2][r]);
            acc[3][r] = fmaf(a[r], wvb[j].w, acc[3][r]);
          }
        }
      }
    }

    // ---- in-wave k-team reduce: xor over lane bits 3..5 (kt), b32 shuffles ----
    #pragma unroll
    for (int c = 0; c < 4; ++c)
      #pragma unroll
      for (int r = 0; r < 8; ++r) {
        float v = acc[c][r];
        v += __shfl_xor(v, 8, 64);
        v += __shfl_xor(v, 16, 64);
        v += __shfl_xor(v, 32, 64);
        acc[c][r] = v;
      }

    // ---- z write: kt-group kt writes row r=kt (static acc indexing, predicated) ----
    #pragma unroll
    for (int r = 0; r < 8; ++r) {
      if (kt == r) {
        #pragma unroll
        for (int c = 0; c < 4; ++c)
          zbuf[(zrow + r) * 33 + (og << 2) + c] = acc[c][r];
      }
    }
    __syncthreads();   // #1: z ready

    // ---- Cell update: fp64 gates + c-state; z is fp32-accurate (as reference) ----
    {
      const bool uact = L ? (p >= 1 && p <= T_) : (p < T_);
      if (uact) {
        const float* za = zbuf + ((L << 5) + ur) * 33 + hj;
        double zi = (double)za[0]   + ub_i;
        double zj = (double)za[264] + ub_j;
        double zf = (double)za[528] + ub_f;
        double zo = (double)za[792] + ub_o;
        cst = cst * sigmd(zf + 1.0) + sigmd(zi) * tanh(zj);
        float hv = (float)(tanh(cst) * sigmd(zo));
        float* hd = L ? (h2g + (((p + 1) & 1) << 11)) : (h1g + ((p & 1) << 11));
        hstoref(hd + (ur << 8) + ucol, hv);
      }
    }

    if (p <= T_) {
      // ---- arrive early, then hide head + x-prefetch in the barrier shadow ----
      __builtin_amdgcn_s_waitcnt(0);
      __syncthreads();   // #2: all waves' h stores drained
      if (tid == 0)
        __hip_atomic_fetch_add(bar, 1u, __ATOMIC_RELAXED, __HIP_MEMORY_SCOPE_AGENT);

      // x prefetch for phase p+1 (no cross-block dependency)
      const int xp1 = (p + 1 < T_) ? (p + 1) : (T_ - 1);
      const float* xb = x + (size_t)(rb0 + sr) * (T_ * 256) + (size_t)xp1 * 256 + skc;
      float xv[4];
      #pragma unroll
      for (int v = 0; v < 4; ++v) xv[v] = xb[v << 6];

      // head t3=p-2 from staged h2 region (Alds [512,768) untouched until after #3)
      if (headblk && p >= 2) do_head(p - 2);

      // x LDS writes: region [0,256) — disjoint from head reads, GEMM long done
      #pragma unroll
      for (int v = 0; v < 4; ++v) Alds[aoff_f((v << 6) + skc) + sr] = xv[v];

      if (tid == 0) {
        const unsigned target = ((unsigned)(p + 2)) << 3;
        while (__hip_atomic_load(bar, __ATOMIC_RELAXED, __HIP_MEMORY_SCOPE_AGENT) < target)
          __builtin_amdgcn_s_sleep(1);
        __asm__ volatile("" ::: "memory");
      }
      __syncthreads();   // #3: group h published

      // ---- stage h1(p), h2(p-1) for phase p+1 ----
      const float* h1p = h1g + ((p & 1) << 11);
      const float* h2p = h2g + (((p + 1) & 1) << 11);
      float hv8[8];
      #pragma unroll
      for (int v = 0; v < 4; ++v) hv8[v] = hloadf(h1p + (sr << 8) + skc + (v << 6));
      #pragma unroll
      for (int v = 0; v < 4; ++v) hv8[4 + v] = hloadf(h2p + (sr << 8) + skc + (v << 6));
      #pragma unroll
      for (int v = 0; v < 8; ++v) Alds[aoff_f(256 + (v << 6) + skc) + sr] = hv8[v];
      __syncthreads();   // #4: A staged for next phase
    } else {
      // final phase: emit last head (t3 = T_-1), no barrier/stage needed
      if (headblk) do_head(p - 2);
    }
  }
}

extern "C" void kernel_launch(void* const* d_in, const int* in_sizes, int n_in,
                              void* d_out, int out_size, void* d_ws, size_t ws_size,
                              hipStream_t stream) {
  const float* x  = (const float*)d_in[0];
  const float* W1 = (const float*)d_in[1];
  const float* b1 = (const float*)d_in[2];
  const float* W2 = (const float*)d_in[3];
  const float* b2 = (const float*)d_in[4];
  const float* Wo = (const float*)d_in[5];
  const float* bo = (const float*)d_in[6];
  float* out = (float*)d_out;
  unsigned char* ws = (unsigned char*)d_ws;

  // Zero barrier counters (first 4 KB of ws); part of the captured graph.
  hipMemsetAsync(d_ws, 0, 4096, stream);

  lstm2_head<<<dim3(256), dim3(512), 0, stream>>>(x, W1, b1, W2, b2, Wo, bo, out, ws);
}

// Round 4
// 6124.719 us; speedup vs baseline: 4.2420x; 1.1532x over previous
//
#include <hip/hip_runtime.h>
#include <math.h>

#define T_ 512

// fp32 fast nonlinearities (reference path is fp32 sigmoid/tanh).
__device__ __forceinline__ float sigf(float x) {
  return __builtin_amdgcn_rcpf(1.0f + __expf(-x));
}
__device__ __forceinline__ float tanhf_(float x) {
  float e = __expf(x + x);                    // inf for large x -> t=1; 0 -> t=-1
  return 1.0f - 2.0f * __builtin_amdgcn_rcpf(e + 1.0f);
}

// Coherent (agent-scope, cache-bypassing) 4-byte load/store for fp32 h exchange.
__device__ __forceinline__ float hloadf(const float* p) {
  unsigned u = __hip_atomic_load((const unsigned*)p,
                                 __ATOMIC_RELAXED, __HIP_MEMORY_SCOPE_AGENT);
  return __builtin_bit_cast(float, u);
}
__device__ __forceinline__ void hstoref(float* p, float v) {
  __hip_atomic_store((unsigned*)p, __builtin_bit_cast(unsigned, v),
                     __ATOMIC_RELAXED, __HIP_MEMORY_SCOPE_AGENT);
}

// fp32 A row kc at Alds + kc*8 + 4*(kc>>6): 32B rows, 16B-aligned (b128-able).
// +4-float stagger per 64-row block puts the 8 in-wave k-team bases at banks
// {4kt}: 8 chunks tile all 32 banks, conflict-free; og-lanes share addresses
// (free broadcast).
__device__ __forceinline__ int aoff_f(int kc) { return (kc << 3) + ((kc >> 6) << 2); }

// Grid 256 = 32 groups x 8 blocks; blockIdx = g*8 + w so XCD (blockIdx%8) == w
// caches only col-slice w's 512 KB of weights in its L2. Group g owns batch rows
// [8g, 8g+8); block w owns h-cols [32w, 32w+32) of BOTH layers.
// GEMM: wave = (layer, gate); lane = (kt 8, og 8). k-team partials combined by
// RECURSIVE HALVING (28 shuffles, each lane ends holding row kt) instead of a
// full 96-shuffle butterfly. Cell update: fp32 gates, fp64 c-state.
__global__ __launch_bounds__(512, 1) void lstm2_head(
    const float* __restrict__ x, const float* __restrict__ W1,
    const float* __restrict__ b1, const float* __restrict__ W2,
    const float* __restrict__ b2, const float* __restrict__ Wo,
    const float* __restrict__ bo, float* __restrict__ out,
    unsigned char* __restrict__ ws)
{
  __shared__ float Alds[6192];   // [kc 768][r 8] stride 8 + stagger (24.8 KB)
  __shared__ float zbuf[2112];   // [(half,gate,r) 64][32 +1 pad] (8.4 KB)

  const int tid = threadIdx.x;
  const int g  = blockIdx.x >> 3;    // 0..31
  const int w  = blockIdx.x & 7;     // 0..7
  const int rb0 = g << 3;

  unsigned* bar = (unsigned*)ws + (g << 4);            // 64B-spaced counters
  float* hbase = (float*)(ws + 4096);
  float* h1g = hbase + (size_t)g * 4096;               // [2 slots][8 r][256] fp32
  float* h2g = hbase + 131072 + (size_t)g * 4096;

  // Zero both slots of both h arrays (redundant across the group's blocks, benign).
  for (int i = tid; i < 4096; i += 512) { hstoref(h1g + i, 0.0f); hstoref(h2g + i, 0.0f); }

  // group barrier #0
  __builtin_amdgcn_s_waitcnt(0);
  __syncthreads();
  if (tid == 0) {
    __hip_atomic_fetch_add(bar, 1u, __ATOMIC_RELAXED, __HIP_MEMORY_SCOPE_AGENT);
    while (__hip_atomic_load(bar, __ATOMIC_RELAXED, __HIP_MEMORY_SCOPE_AGENT) < 8u) {}
    __asm__ volatile("" ::: "memory");
  }
  __syncthreads();

  // ---- GEMM mapping ----
  const int lane = tid & 63;
  const int wvid = tid >> 6;               // wave 0..7
  const int half = wvid >> 2;              // 0 = layer1, 1 = layer2
  const int gate = wvid & 3;               // i,j,f,o
  const int kt   = lane >> 3;              // in-wave k-team 0..7 (K=64 each)
  const int og   = lane & 7;               // col-quad within the 32-col slice
  const bool b5 = (lane & 32) != 0;        // kt bit2
  const bool b4 = (lane & 16) != 0;        // kt bit1
  const bool b3 = (lane & 8) != 0;         // kt bit0
  const float* wbase = (half ? W2 : W1)
      + (size_t)(kt << 6) * 1024 + (gate << 8) + (w << 5) + (og << 2);
  const int kc0  = (half << 8) + (kt << 6);
  const int zrow = ((half << 2) + gate) << 3;

  // ---- staging mapping ----
  const int sr  = tid & 7;                 // A-row
  const int skc = tid >> 3;                // 0..63

  // ---- update mapping: one cell per thread (fp32 gates, fp64 c-state) ----
  const int L  = tid >> 8;
  const int ur = (tid >> 5) & 7;
  const int hj = tid & 31;
  const float* ubb = L ? b2 : b1;
  const int ucol = (w << 5) + hj;
  const float ub_i = ubb[ucol];
  const float ub_j = ubb[256 + ucol];
  const float ub_f = ubb[512 + ucol] + 1.0f;   // forget bias folded
  const float ub_o = ubb[768 + ucol];
  double cst = 0.0;

  // ---- head (block w==0): wave v owns row v; lane owns h2-cols {lane,64+,128+,192+}
  const bool headblk = (w == 0);
  float wo_r[4][6];
  float bo_r[6];
  if (headblk) {
    #pragma unroll
    for (int q = 0; q < 4; ++q)
      #pragma unroll
      for (int c = 0; c < 6; ++c) wo_r[q][c] = Wo[(lane + (q << 6)) * 6 + c];
    #pragma unroll
    for (int c = 0; c < 6; ++c) bo_r[c] = bo[c];
  }

  auto do_head = [&](int t3) {
    float pr[6] = {0, 0, 0, 0, 0, 0};
    #pragma unroll
    for (int q = 0; q < 4; ++q) {
      float hv = Alds[aoff_f(512 + lane + (q << 6)) + wvid];
      #pragma unroll
      for (int c = 0; c < 6; ++c) pr[c] = fmaf(hv, wo_r[q][c], pr[c]);
    }
    #pragma unroll
    for (int off = 1; off <= 32; off <<= 1)
      #pragma unroll
      for (int c = 0; c < 6; ++c) pr[c] += __shfl_xor(pr[c], off, 64);
    if (lane == 0) {
      size_t orow = (((size_t)(rb0 + wvid)) << 9) + (size_t)t3;   // b*T + t
      #pragma unroll
      for (int c = 0; c < 6; ++c) {
        float lg = pr[c] + bo_r[c];
        out[orow * 6 + c] = lg;
        float pd = (lg > 0.0f) ? 1.0f : 0.0f;      // 0.5 < sigmoid <=> lg > 0
        out[(size_t)786432 + orow * 6 + c] = pd;   // condition
        out[(size_t)1572864 + orow * 6 + c] = pd;  // prediction
      }
    }
  };

  // ---- prologue stage for phase 0: x(0), h1(-1)=0, h2(-2)=0 ----
  {
    const float* xb = x + (size_t)(rb0 + sr) * (T_ * 256) + skc;   // t=0
    float sv[12];
    #pragma unroll
    for (int v = 0; v < 4; ++v) sv[v] = xb[v << 6];
    const float* h1p = h1g + 2048;   // slot 1 (zeroed)
    const float* h2p = h2g;          // slot 0 (zeroed)
    #pragma unroll
    for (int v = 0; v < 4; ++v) sv[4 + v] = hloadf(h1p + (sr << 8) + skc + (v << 6));
    #pragma unroll
    for (int v = 0; v < 4; ++v) sv[8 + v] = hloadf(h2p + (sr << 8) + skc + (v << 6));
    #pragma unroll
    for (int v = 0; v < 12; ++v) Alds[aoff_f((v << 6) + skc) + sr] = sv[v];
  }
  __syncthreads();

  // Weights are phase-invariant: first 8-k batch is loop-carried in wva and
  // reloaded each phase inside the barrier shadow (L2 latency hidden).
  float4 wva[8];
  #pragma unroll
  for (int j = 0; j < 8; ++j) wva[j] = *(const float4*)(wbase + (size_t)j * 1024);

  // Phase p: layer1(t=p), layer2(t=p-1), head(t=p-2).
  #pragma unroll 1
  for (int p = 0; p <= T_ + 1; ++p) {
    // ---- GEMM: lane covers 4 gate-cols x 8 rows over k in [64kt, 64kt+64).
    // 8+8 float4 ping-pong: ~8 loads in flight, 8 k-steps (128 SIMD-cyc) of
    // lookahead to cover L2 latency. Fits the 256-VGPR budget (1 block/CU).
    float acc[4][8];
    #pragma unroll
    for (int c = 0; c < 4; ++c)
      #pragma unroll
      for (int r = 0; r < 8; ++r) acc[c][r] = 0.0f;
    {
      const float* ap = Alds + aoff_f(kc0);
      float4 wvb[8];
      #pragma unroll 1
      for (int sg = 0; sg < 4; ++sg) {
        const int s0 = sg << 4;
        #pragma unroll
        for (int j = 0; j < 8; ++j)
          wvb[j] = *(const float4*)(wbase + (size_t)(s0 + 8 + j) * 1024);
        #pragma unroll
        for (int j = 0; j < 8; ++j) {
          const float* apj = ap + ((s0 + j) << 3);
          float4 a0 = *(const float4*)(apj);
          float4 a1 = *(const float4*)(apj + 4);
          float a[8] = {a0.x, a0.y, a0.z, a0.w, a1.x, a1.y, a1.z, a1.w};
          #pragma unroll
          for (int r = 0; r < 8; ++r) {
            acc[0][r] = fmaf(a[r], wva[j].x, acc[0][r]);
            acc[1][r] = fmaf(a[r], wva[j].y, acc[1][r]);
            acc[2][r] = fmaf(a[r], wva[j].z, acc[2][r]);
            acc[3][r] = fmaf(a[r], wva[j].w, acc[3][r]);
          }
        }
        if (sg < 3) {
          #pragma unroll
          for (int j = 0; j < 8; ++j)
            wva[j] = *(const float4*)(wbase + (size_t)(s0 + 16 + j) * 1024);
        }
        #pragma unroll
        for (int j = 0; j < 8; ++j) {
          const float* apj = ap + ((s0 + 8 + j) << 3);
          float4 a0 = *(const float4*)(apj);
          float4 a1 = *(const float4*)(apj + 4);
          float a[8] = {a0.x, a0.y, a0.z, a0.w, a1.x, a1.y, a1.z, a1.w};
          #pragma unroll
          for (int r = 0; r < 8; ++r) {
            acc[0][r] = fmaf(a[r], wvb[j].x, acc[0][r]);
            acc[1][r] = fmaf(a[r], wvb[j].y, acc[1][r]);
            acc[2][r] = fmaf(a[r], wvb[j].z, acc[2][r]);
            acc[3][r] = fmaf(a[r], wvb[j].w, acc[3][r]);
          }
        }
      }
    }

    // ---- reduce-scatter over the 8 k-teams (recursive halving, 28 shuffles).
    // Each round: send the half the partner keeps, keep own half, add recv.
    // After 3 rounds lane (kt,og) holds the full sum for row kt, cols og*4+c.
    float tA[4][4];
    #pragma unroll
    for (int c = 0; c < 4; ++c)
      #pragma unroll
      for (int q = 0; q < 4; ++q) {
        float send = b5 ? acc[c][q] : acc[c][q + 4];
        float keep = b5 ? acc[c][q + 4] : acc[c][q];
        tA[c][q] = keep + __shfl_xor(send, 32, 64);
      }
    float tB[4][2];
    #pragma unroll
    for (int c = 0; c < 4; ++c)
      #pragma unroll
      for (int q = 0; q < 2; ++q) {
        float send = b4 ? tA[c][q] : tA[c][q + 2];
        float keep = b4 ? tA[c][q + 2] : tA[c][q];
        tB[c][q] = keep + __shfl_xor(send, 16, 64);
      }
    #pragma unroll
    for (int c = 0; c < 4; ++c) {
      float send = b3 ? tB[c][0] : tB[c][1];
      float keep = b3 ? tB[c][1] : tB[c][0];
      float zv = keep + __shfl_xor(send, 8, 64);
      zbuf[(zrow + kt) * 33 + (og << 2) + c] = zv;   // 2-way banks: free
    }
    __syncthreads();   // #1: z ready

    // ---- Cell update: fp32 gates (v_exp_f32), fp64 c-state accumulate ----
    {
      const bool uact = L ? (p >= 1 && p <= T_) : (p < T_);
      if (uact) {
        const float* za = zbuf + ((L << 5) + ur) * 33 + hj;
        float si = sigf(za[0]   + ub_i);
        float tj = tanhf_(za[264] + ub_j);
        float sf = sigf(za[528] + ub_f);
        float so = sigf(za[792] + ub_o);
        cst = cst * (double)sf + (double)(si * tj);
        float hv = tanhf_((float)cst) * so;
        float* hd = L ? (h2g + (((p + 1) & 1) << 11)) : (h1g + ((p & 1) << 11));
        hstoref(hd + (ur << 8) + ucol, hv);
      }
    }

    if (p <= T_) {
      // head BEFORE the drain: w0's head work hides its own store latency,
      // shortening the group's slowest-arrival path.
      if (headblk && p >= 2) do_head(p - 2);

      __builtin_amdgcn_s_waitcnt(0);
      __syncthreads();   // #2: all waves' h stores drained
      if (tid == 0)
        __hip_atomic_fetch_add(bar, 1u, __ATOMIC_RELAXED, __HIP_MEMORY_SCOPE_AGENT);

      // ---- barrier shadow: x(p+1) prefetch + next-phase weight batch ----
      const int xp1 = (p + 1 < T_) ? (p + 1) : (T_ - 1);
      const float* xb = x + (size_t)(rb0 + sr) * (T_ * 256) + (size_t)xp1 * 256 + skc;
      float xv[4];
      #pragma unroll
      for (int v = 0; v < 4; ++v) xv[v] = xb[v << 6];
      #pragma unroll
      for (int v = 0; v < 4; ++v) Alds[aoff_f((v << 6) + skc) + sr] = xv[v];

      #pragma unroll
      for (int j = 0; j < 8; ++j) wva[j] = *(const float4*)(wbase + (size_t)j * 1024);

      if (tid == 0) {
        const unsigned target = ((unsigned)(p + 2)) << 3;
        while (__hip_atomic_load(bar, __ATOMIC_RELAXED, __HIP_MEMORY_SCOPE_AGENT) < target) {}
        __asm__ volatile("" ::: "memory");
      }
      __syncthreads();   // #3: group h published

      // ---- stage h1(p), h2(p-1) for phase p+1 ----
      const float* h1p = h1g + ((p & 1) << 11);
      const float* h2p = h2g + (((p + 1) & 1) << 11);
      float hv8[8];
      #pragma unroll
      for (int v = 0; v < 4; ++v) hv8[v] = hloadf(h1p + (sr << 8) + skc + (v << 6));
      #pragma unroll
      for (int v = 0; v < 4; ++v) hv8[4 + v] = hloadf(h2p + (sr << 8) + skc + (v << 6));
      #pragma unroll
      for (int v = 0; v < 8; ++v) Alds[aoff_f(256 + (v << 6) + skc) + sr] = hv8[v];
      __syncthreads();   // #4: A staged for next phase
    } else {
      // final phase: emit last head (t3 = T_-1), no barrier/stage needed
      if (headblk) do_head(p - 2);
    }
  }
}

extern "C" void kernel_launch(void* const* d_in, const int* in_sizes, int n_in,
                              void* d_out, int out_size, void* d_ws, size_t ws_size,
                              hipStream_t stream) {
  const float* x  = (const float*)d_in[0];
  const float* W1 = (const float*)d_in[1];
  const float* b1 = (const float*)d_in[2];
  const float* W2 = (const float*)d_in[3];
  const float* b2 = (const float*)d_in[4];
  const float* Wo = (const float*)d_in[5];
  const float* bo = (const float*)d_in[6];
  float* out = (float*)d_out;
  unsigned char* ws = (unsigned char*)d_ws;

  // Zero barrier counters (first 4 KB of ws); part of the captured graph.
  hipMemsetAsync(d_ws, 0, 4096, stream);

  lstm2_head<<<dim3(256), dim3(512), 0, stream>>>(x, W1, b1, W2, b2, Wo, bo, out, ws);
}